// Round 10
// baseline (182.921 us; speedup 1.0000x reference)
//
#include <hip/hip_runtime.h>
#include <stdint.h>

typedef unsigned short u16;
typedef __attribute__((ext_vector_type(8))) short bfrag;   // 8 x bf16 (4 VGPRs)
typedef __attribute__((ext_vector_type(4))) short bfrag4;  // 4 x bf16 (2 VGPRs)
typedef __attribute__((ext_vector_type(4))) float f32x4;   // MFMA C/D

#define MFMA_BF16 __builtin_amdgcn_mfma_f32_16x16x32_bf16

static constexpr int Bc = 2;      // batch
static constexpr int Tc = 2048;   // seq
static constexpr int Cc = 1024;   // channels
static constexpr int Hc = 16;     // heads
static constexpr int Dc = 64;     // head dim
static constexpr int N2 = 2 * Cc; // 2048, packed QK row length

__device__ __forceinline__ u16 f2bf(float f) {
    union { unsigned int i; float f; } v; v.f = f;
    unsigned int u = v.i;
    u += 0x7fffu + ((u >> 16) & 1u);   // round-to-nearest-even
    return (u16)(u >> 16);
}
__device__ __forceinline__ unsigned int fbits(float f) {
    union { unsigned int i; float f; } v; v.f = f; return v.i;
}
// pack two f32 -> two bf16 (truncation) in ONE v_perm_b32: {hi.bf16, lo.bf16}
__device__ __forceinline__ unsigned int pack_bf2(float hi, float lo) {
    return __builtin_amdgcn_perm(fbits(hi), fbits(lo), 0x07060302u);
}

// K=16 MFMA for PV (S^T C-layout == B-operand layout)
#if __has_builtin(__builtin_amdgcn_mfma_f32_16x16x16bf16_1k)
__device__ __forceinline__ f32x4 MFMA16(bfrag4 a, bfrag4 b, f32x4 c) {
    return __builtin_amdgcn_mfma_f32_16x16x16bf16_1k(a, b, c, 0, 0, 0);
}
#elif __has_builtin(__builtin_amdgcn_mfma_f32_16x16x16_bf16)
__device__ __forceinline__ f32x4 MFMA16(bfrag4 a, bfrag4 b, f32x4 c) {
    return __builtin_amdgcn_mfma_f32_16x16x16_bf16(a, b, c, 0, 0, 0);
}
#else
__device__ __forceinline__ f32x4 MFMA16(bfrag4 a, bfrag4 b, f32x4 c) {
    bfrag a8 = {a[0], a[1], a[2], a[3], 0, 0, 0, 0};
    bfrag b8 = {b[0], b[1], b[2], b[3], 0, 0, 0, 0};
    return MFMA_BF16(a8, b8, c, 0, 0, 0);
}
#endif

// async global -> LDS, 16B per lane; deposits at lds + lane*16.
__device__ __forceinline__ void async_load16(const u16* g, u16* lds) {
    __builtin_amdgcn_global_load_lds(
        (const __attribute__((address_space(1))) unsigned int*)g,
        (__attribute__((address_space(3))) unsigned int*)lds, 16, 0, 0);
}

// ---------------------------------------------------------------------------
// Fused prep: blocks [0,4096) cvt x->bf16; [4096,7168) w_qkv T; [7168,8192) w_out T
// ---------------------------------------------------------------------------
__global__ __launch_bounds__(256) void prep(
    const float* __restrict__ x, const float* __restrict__ w_qkv,
    const float* __restrict__ w_out, u16* __restrict__ xb,
    u16* __restrict__ WqkvT, u16* __restrict__ WoutT) {
    __shared__ u16 tile[32][33];
    const int blk = blockIdx.x, tid = threadIdx.x;
    if (blk < 4096) {
        const int i = (blk * 256 + tid) * 4;
        const float4 v = *(const float4*)(x + i);
        ushort4 o;
        o.x = f2bf(v.x); o.y = f2bf(v.y); o.z = f2bf(v.z); o.w = f2bf(v.w);
        *(ushort4*)(xb + i) = o;
        return;
    }
    const int tx = tid & 31, ty = tid >> 5;   // 32 x 8
    const float* in; u16* out; int rows, cols, c0, r0;
    if (blk < 4096 + 3072) {
        const int t = blk - 4096;            // grid (96, 32)
        in = w_qkv; out = WqkvT; rows = 1024; cols = 3072;
        c0 = (t % 96) * 32; r0 = (t / 96) * 32;
    } else {
        const int t = blk - 7168;            // grid (32, 32)
        in = w_out; out = WoutT; rows = 1024; cols = 1024;
        c0 = (t & 31) * 32; r0 = (t >> 5) * 32;
    }
    for (int i = 0; i < 4; i++)
        tile[ty + 8 * i][tx] = f2bf(in[(size_t)(r0 + ty + 8 * i) * cols + c0 + tx]);
    __syncthreads();
    for (int i = 0; i < 4; i++)
        out[(size_t)(c0 + ty + 8 * i) * rows + r0 + tx] = tile[tx][ty + 8 * i];
}

// ---------------------------------------------------------------------------
// GEMM, double-buffered single-barrier K-loop (BK=32):
//   stage(0); for t: { sync; prefetch(t+1, other buf); compute(t) }
// Buffer selection by INTEGER OFFSET into one __shared__ array (no generic-
// pointer arrays of LDS addresses -- that fails gfx950 codegen).
// LDS per buffer: 128 rows x 32 elems, two 64B rows packed per 128B line;
// 16B chunk swizzle c_stored = c_global ^ ((r>>1)&3) -> frag reads 2-way/bank.
// MODE 0: out fp32 row-major [M][Nn].
// MODE 1 (QKV): n0 <  2048 -> packed bf16 QK [M][2048];
//               n0 >= 2048 -> V transposed into Vt [B*H][D][T] via LDS
//               (epilogue reuses the staging LDS; stride 136 keeps b128 aligned).
// ---------------------------------------------------------------------------
template <int MODE>
__global__ __launch_bounds__(256) void gemm_bt(
    const u16* __restrict__ A, const u16* __restrict__ BT,
    const float* __restrict__ bias, void* __restrict__ out_p,
    u16* __restrict__ Vt, int M, int Nn, int K) {
    constexpr int SELEMS = (MODE == 1) ? 128 * 136 : 4 * 4096;
    __shared__ __align__(16) u16 smem[SELEMS];
    // buffer layout: A0 @0, A1 @4096, B0 @8192, B1 @12288

    const int tid  = threadIdx.x;
    const int wave = tid >> 6, lane = tid & 63;
    const int quad = lane >> 4, l16 = lane & 15;
    const int wm = wave & 1, wn = wave >> 1;
    const int m0 = blockIdx.y * 128, n0 = blockIdx.x * 128;

    f32x4 acc[4][4];
    #pragma unroll
    for (int i = 0; i < 4; i++)
        #pragma unroll
        for (int j = 0; j < 4; j++)
            acc[i][j] = (f32x4){0.f, 0.f, 0.f, 0.f};

    // staging lane geometry (per wave-instr window = 16 rows x 64B):
    const int rloc = 2 * (lane >> 3) + ((lane >> 2) & 1);
    const int cg   = ((lane & 3) ^ ((lane >> 3) & 3)) * 8;
    // fragment-read un-swizzle
    const int rk   = (l16 >> 1) & 3;
    const int rodd = (l16 & 1) * 32;

    const int T = K >> 5;
    #define STAGE(t, bsel)                                                      \
        {                                                                       \
            const int k0_ = (t) << 5;                                           \
            const int ao_ = (bsel) * 4096;                                      \
            _Pragma("unroll")                                                   \
            for (int j = 0; j < 2; j++) {                                       \
                const int R0 = wave * 32 + j * 16;                              \
                async_load16(A  + (size_t)(m0 + R0 + rloc) * K + k0_ + cg,      \
                             smem + ao_ + R0 * 32);                             \
                async_load16(BT + (size_t)(n0 + R0 + rloc) * K + k0_ + cg,      \
                             smem + 8192 + ao_ + R0 * 32);                      \
            }                                                                   \
        }

    STAGE(0, 0);
    for (int t = 0; t < T; t++) {
        __syncthreads();                      // drains stage(t); frees buf (t+1)&1
        if (t + 1 < T) STAGE(t + 1, (t + 1) & 1);
        const u16* Ab = smem + (t & 1) * 4096;
        const u16* Bb = smem + 8192 + (t & 1) * 4096;
        bfrag af[4], bf[4];
        #pragma unroll
        for (int mt = 0; mt < 4; mt++) {
            const int r = wm * 64 + mt * 16 + l16;
            af[mt] = *(const bfrag*)(Ab + (r >> 1) * 64 + rodd + (quad ^ rk) * 8);
        }
        #pragma unroll
        for (int nt = 0; nt < 4; nt++) {
            const int r = wn * 64 + nt * 16 + l16;
            bf[nt] = *(const bfrag*)(Bb + (r >> 1) * 64 + rodd + (quad ^ rk) * 8);
        }
        #pragma unroll
        for (int mt = 0; mt < 4; mt++)
            #pragma unroll
            for (int nt = 0; nt < 4; nt++)
                acc[mt][nt] = MFMA_BF16(af[mt], bf[nt], acc[mt][nt], 0, 0, 0);
    }
    #undef STAGE

    if (MODE == 1 && n0 >= 2048) {
        // ---- V block: transpose through LDS into Vt [B*H][D][T] ----
        __syncthreads();   // all waves' K-loop LDS reads complete
        #pragma unroll
        for (int nt = 0; nt < 4; nt++) {
            const int ln = wn * 64 + nt * 16 + l16;
            const float bv = bias[n0 + ln];
            u16* col = smem + ln * 136;        // [n][m], stride 136
            #pragma unroll
            for (int mt = 0; mt < 4; mt++) {
                const int lmb = wm * 64 + mt * 16 + quad * 4;
                #pragma unroll
                for (int r = 0; r < 4; r++)
                    col[lmb + r] = f2bf(acc[mt][nt][r] + bv);
            }
        }
        __syncthreads();
        const int bb = m0 >> 11, t0 = m0 & 2047;
        const int h0 = (n0 - 2048) >> 6;       // first of the 2 heads in this tile
        const int dl = tid >> 1;               // local col 0..127
        const int th = (tid & 1) * 64;         // t-half
        u16* dst = Vt + ((size_t)(bb * Hc + h0 + (dl >> 6)) * Dc + (dl & 63)) * Tc
                      + t0 + th;
        const u16* srcr = smem + dl * 136 + th;
        #pragma unroll
        for (int c = 0; c < 8; c++)
            *(uint4*)(dst + c * 8) = *(const uint4*)(srcr + c * 8);
    } else {
        #pragma unroll
        for (int nt = 0; nt < 4; nt++) {
            const int gn = n0 + wn * 64 + nt * 16 + l16;
            const float bv = bias[gn];
            #pragma unroll
            for (int mt = 0; mt < 4; mt++) {
                #pragma unroll
                for (int r = 0; r < 4; r++) {
                    const int gm = m0 + wm * 64 + mt * 16 + quad * 4 + r;
                    if (MODE == 1)
                        ((u16*)out_p)[(size_t)gm * Nn + gn] = f2bf(acc[mt][nt][r] + bv);
                    else
                        ((float*)out_p)[(size_t)gm * Nn + gn] = acc[mt][nt][r] + bv;
                }
            }
        }
    }
}

// ---------------------------------------------------------------------------
// Causal flash attention, S^T register-resident P, double-buffered K/V staging.
// Q,K from packed QK [B*T][2C] (row stride 2C).  Vt: [B*H][D][T] bf16.
// ---------------------------------------------------------------------------
__global__ __launch_bounds__(256, 4) void attn_kernel(
    const u16* __restrict__ QKp, const u16* __restrict__ Vt,
    u16* __restrict__ Ob) {
    __shared__ __align__(16) u16 KsF[2][64 * 64];   // [key][d-chunk-swizzled]
    __shared__ __align__(16) u16 VsF[2][64 * 64];   // [d][key-chunk-swizzled]

    const int tid  = threadIdx.x;
    const int wave = tid >> 6, lane = tid & 63;
    const int quad = lane >> 4, l16 = lane & 15;

    const int bh = blockIdx.x & 31;               // same-XCD head grouping
    const int jq = 31 - (blockIdx.x >> 5);        // q-tile (64 rows), longest first
    const int b = bh >> 4, h = bh & 15;
    const u16* Qp = QKp + (size_t)b * Tc * N2 + h * Dc;   // row t: + t*N2
    const u16* Kp = Qp + Cc;
    const u16* Vp = Vt + (size_t)bh * Dc * Tc;

    const int qw = jq * 64 + wave * 16;           // this wave's base q row

    // staging lane geometry: 1KB/instr = 8 rows x 8 chunks of 16B
    const int row8 = lane >> 3;
    const int swz  = ((lane & 7) ^ row8) * 8;
    // K-frag un-swizzled chunk offsets (elems)
    const int pk0 = ((quad)     ^ (l16 & 7)) * 8;
    const int pk1 = ((quad + 4) ^ (l16 & 7)) * 8;

    // Q fragments: lane = q (n-side), regs = d
    bfrag qf0, qf1;
    {
        const u16* qp = Qp + (size_t)(qw + l16) * N2 + quad * 8;
        qf0 = *(const bfrag*)qp;
        qf1 = *(const bfrag*)(qp + 32);
    }

    float l_i = 0.f;
    f32x4 oacc[4];                                // O^T tiles: lane=q, reg->d
    #pragma unroll
    for (int g = 0; g < 4; g++) oacc[g] = (f32x4){0.f, 0.f, 0.f, 0.f};

    #define STAGEKV(t, bsel)                                                    \
        {                                                                       \
            const int k0_ = (t) * 64;                                           \
            _Pragma("unroll")                                                   \
            for (int j = 0; j < 2; j++) {                                       \
                const int rr = wave * 16 + j * 8;                               \
                const int gr = rr + row8;                                       \
                async_load16(Kp + (size_t)(k0_ + gr) * N2 + swz,                \
                             &KsF[bsel][rr * 64]);                              \
                async_load16(Vp + (size_t)gr * Tc + k0_ + swz,                  \
                             &VsF[bsel][rr * 64]);                              \
            }                                                                   \
        }

    STAGEKV(0, 0);
    for (int t = 0; t <= jq; t++) {
        __syncthreads();                       // drains stage(t)
        if (t < jq) STAGEKV(t + 1, (t + 1) & 1);
        const u16* Kb = KsF[t & 1];
        const u16* Vb = VsF[t & 1];

        // ---- S^T = K @ Q^T : 64 keys (regs) x 16 q (lanes) ----
        f32x4 s[4];
        #pragma unroll
        for (int g = 0; g < 4; g++) {
            const u16* kb = Kb + (g * 16 + l16) * 64;
            bfrag kf0 = *(const bfrag*)(kb + pk0);
            bfrag kf1 = *(const bfrag*)(kb + pk1);
            f32x4 z = (f32x4){0.f, 0.f, 0.f, 0.f};
            z = MFMA_BF16(kf0, qf0, z, 0, 0, 0);
            z = MFMA_BF16(kf1, qf1, z, 0, 0, 0);
            s[g] = z;   // s[g][r] = score(q=qw+l16, key=k0+g*16+quad*4+r)
        }

        // ---- streaming softmax numerators (all in-lane) ----
        #pragma unroll
        for (int g = 0; g < 4; g++)
            #pragma unroll
            for (int r = 0; r < 4; r++)
                s[g][r] = __expf(s[g][r] * 0.125f);
        if (t == jq) {   // diagonal tile: zero keys above the diagonal
            #pragma unroll
            for (int g = 0; g < 4; g++)
                #pragma unroll
                for (int r = 0; r < 4; r++)
                    if (g * 16 + quad * 4 + r > wave * 16 + l16) s[g][r] = 0.f;
        }
        #pragma unroll
        for (int g = 0; g < 4; g++)
            l_i += s[g][0] + s[g][1] + s[g][2] + s[g][3];

        // ---- O^T += V^T @ P^T : P packed in-register (v_perm truncation) ----
        #pragma unroll
        for (int g = 0; g < 4; g++) {
            union { unsigned int u[2]; bfrag4 v; } pf;
            pf.u[0] = pack_bf2(s[g][1], s[g][0]);
            pf.u[1] = pack_bf2(s[g][3], s[g][2]);
            const int vc = ((2 * g + (quad >> 1)) ^ (l16 & 7)) * 8 + (quad & 1) * 4;
            #pragma unroll
            for (int ng = 0; ng < 4; ng++) {
                const bfrag4 vf = *(const bfrag4*)(Vb + (ng * 16 + l16) * 64 + vc);
                oacc[ng] = MFMA16(vf, pf.v, oacc[ng]);
            }
        }
    }
    #undef STAGEKV

    // ---- epilogue: reduce l over quads, normalize, store O ----
    float rs = l_i;
    rs += __shfl_xor(rs, 16);
    rs += __shfl_xor(rs, 32);
    const float inv = 1.f / rs;
    const int q = qw + l16;
    u16* orow = Ob + (size_t)(b * Tc + q) * Cc + h * Dc + quad * 4;
    #pragma unroll
    for (int ng = 0; ng < 4; ng++) {
        ushort4 o;
        o.x = f2bf(oacc[ng][0] * inv);
        o.y = f2bf(oacc[ng][1] * inv);
        o.z = f2bf(oacc[ng][2] * inv);
        o.w = f2bf(oacc[ng][3] * inv);
        *(ushort4*)(orow + ng * 16) = o;
    }
}

// ---------------------------------------------------------------------------
extern "C" void kernel_launch(void* const* d_in, const int* in_sizes, int n_in,
                              void* d_out, int out_size, void* d_ws, size_t ws_size,
                              hipStream_t stream) {
    const float* x     = (const float*)d_in[0];   // [B*T][C] fp32
    const float* w_qkv = (const float*)d_in[1];   // [C][3C] fp32
    const float* b_qkv = (const float*)d_in[2];   // [3C] fp32
    const float* w_out = (const float*)d_in[3];   // [C][C] fp32
    const float* b_out = (const float*)d_in[4];   // [C] fp32
    float* out = (float*)d_out;                   // [B*T][C] fp32
    u16* ws  = (u16*)d_ws;

    u16* xb    = ws;                               // [4096][1024] bf16 (x)
    u16* WqkvT = xb    + (size_t)4096 * 1024;      // [3072][1024]
    u16* WoutT = WqkvT + (size_t)3072 * 1024;      // [1024][1024]
    u16* QKp   = WoutT + (size_t)1024 * 1024;      // [4096][2048] packed Q,K
    u16* Vt    = QKp   + (size_t)4096 * 2048;      // [B*H][D][T]
    u16* Ao    = xb;                               // alias: xb consumed by GEMM1

    prep<<<8192, 256, 0, stream>>>(x, w_qkv, w_out, xb, WqkvT, WoutT);
    gemm_bt<1><<<dim3(3072 / 128, 4096 / 128), 256, 0, stream>>>(
        xb, WqkvT, b_qkv, QKp, Vt, 4096, 2048, 1024);
    attn_kernel<<<1024, 256, 0, stream>>>(QKp, Vt, Ao);
    gemm_bt<0><<<dim3(1024 / 128, 4096 / 128), 256, 0, stream>>>(
        Ao, WoutT, b_out, out, nullptr, 4096, 1024, 1024);
}